// Round 3
// baseline (329.950 us; speedup 1.0000x reference)
//
#include <hip/hip_runtime.h>
#include <cmath>

// Shapes:
//  fused  [16,64,128,128] f32
//  hf1    [16, 9,256,256] f32
//  hf2    [16, 9,128,128] f32
//  conv_w [3,64,3,3] f32, conv_b [3] f32
//  out    [16,3,512,512] f32
//
// Kernel A: conv partial sums over ic-chunks (NO tanh) -> d_ws [NCHUNK][16][3][128][128]
//   (ic split 4-ways: 2048 blocks -> 8 blocks/CU -> 100% occupancy; round-2 profile
//    showed 512 blocks -> 21% occupancy, latency-bound at 68 us)
// Kernel B: iwt2 sums partials + bias + tanh, then fused double inverse-Haar.

#define H1 128
#define W1 128
#define H2 256
#define W2 256
#define H3 512
#define W3 512
#define IN_CH 64
#define NB 16
#define PLANE (H1 * W1)            // 16384
#define LLSZ (NB * 3 * PLANE)      // 786432 floats per chunk

template <int ICP>
__global__ __launch_bounds__(256, 8) void conv_part_kernel(
    const float* __restrict__ fused,
    const float* __restrict__ cw,
    float* __restrict__ part)
{
    // block (64,4); grid (64/ICP, 32, 16)
    const int tx    = threadIdx.x;
    const int ty    = threadIdx.y;
    const int chunk = blockIdx.x;
    const int h     = blockIdx.y * 4 + ty;
    const int b     = blockIdx.z;
    const int w0    = tx * 2;

    float acc[3][2];
    #pragma unroll
    for (int oc = 0; oc < 3; ++oc) { acc[oc][0] = 0.f; acc[oc][1] = 0.f; }

    const float* fc = fused + ((size_t)b * IN_CH + chunk * ICP) * PLANE;

    float va[3][4], vb[3][4];

    auto ldrow = [&](float v[3][4], const float* p) {
        #pragma unroll
        for (int r = 0; r < 3; ++r) {
            const int hh = h + r - 1;
            const bool hv = ((unsigned)hh) < (unsigned)H1;
            const float* row = p + hh * W1;
            v[r][0] = (hv && (w0 > 0)) ? row[w0 - 1] : 0.f;
            if (hv) {
                float2 m = *(const float2*)(row + w0);
                v[r][1] = m.x; v[r][2] = m.y;
            } else { v[r][1] = 0.f; v[r][2] = 0.f; }
            v[r][3] = (hv && ((w0 + 2) < W1)) ? row[w0 + 2] : 0.f;
        }
    };

    auto comp = [&](const float v[3][4], int ic) {
        #pragma unroll
        for (int oc = 0; oc < 3; ++oc) {
            const float* wp = cw + (oc * IN_CH + chunk * ICP + ic) * 9;  // uniform -> s_load
            #pragma unroll
            for (int kh = 0; kh < 3; ++kh) {
                #pragma unroll
                for (int kw = 0; kw < 3; ++kw) {
                    const float wv = wp[kh * 3 + kw];
                    acc[oc][0] = fmaf(v[kh][kw],     wv, acc[oc][0]);
                    acc[oc][1] = fmaf(v[kh][kw + 1], wv, acc[oc][1]);
                }
            }
        }
    };

    // 2-deep software pipeline: loads for ic+1 in flight during compute of ic.
    ldrow(va, fc);
    #pragma unroll 2
    for (int ic = 0; ic < ICP; ic += 2) {
        ldrow(vb, fc + (size_t)(ic + 1) * PLANE);
        comp(va, ic);
        if (ic + 2 < ICP) ldrow(va, fc + (size_t)(ic + 2) * PLANE);
        comp(vb, ic + 1);
    }

    const size_t base = (size_t)chunk * LLSZ + (((size_t)b * 3) * H1 + h) * W1 + w0;
    #pragma unroll
    for (int oc = 0; oc < 3; ++oc) {
        float2 o; o.x = acc[oc][0]; o.y = acc[oc][1];
        *(float2*)(part + base + (size_t)oc * PLANE) = o;
    }
}

// Fused double inverse-Haar; 2 coarse px/thread; sums NCHUNK conv partials + bias + tanh.
template <int NCHUNK>
__global__ __launch_bounds__(256) void iwt2_kernel(
    const float* __restrict__ part,  // [NCHUNK][16][3][128][128]
    const float* __restrict__ cb,    // [3]
    const float* __restrict__ hf2,   // [16,9,128,128]
    const float* __restrict__ hf1,   // [16,9,256,256]
    float* __restrict__ out)         // [16,3,512,512]
{
    const int idx = blockIdx.x * 256 + threadIdx.x;   // 393216 total
    const int w0 = (idx & 63) * 2;                    // coarse w, even
    const int h  = (idx >> 6) & (H1 - 1);
    const int rest = idx >> 13;                       // 0..47
    const int c = rest % 3;
    const int b = rest / 3;

    // ll pair (pre-tanh partial sum)
    const size_t llbase = (((size_t)(b * 3 + c)) * H1 + h) * W1 + w0;
    float sx = 0.f, sy = 0.f;
    #pragma unroll
    for (int k = 0; k < NCHUNK; ++k) {
        float2 p = *(const float2*)(part + (size_t)k * LLSZ + llbase);
        sx += p.x; sy += p.y;
    }
    const float bias = cb[c];
    float llv[2];
    llv[0] = tanhf(sx + bias);
    llv[1] = tanhf(sy + bias);

    // hf2 -> mid[x][p][q] for the 2 coarse px
    const float* h2p = hf2 + (((size_t)b * 9 + 3 * c) * H1 + h) * W1 + w0;
    float mid[2][2][2];
    #pragma unroll
    for (int j = 0; j < 1; ++j) {} // (keep compiler happy about unroll scopes)
    {
        const float2 A = *(const float2*)(h2p);
        const float2 Bv = *(const float2*)(h2p + PLANE);
        const float2 Cv = *(const float2*)(h2p + 2 * PLANE);
        const float a[2] = { A.x * 2.f - 1.f,  A.y * 2.f - 1.f };
        const float bq[2] = { Bv.x * 2.f - 1.f, Bv.y * 2.f - 1.f };
        const float cq[2] = { Cv.x * 2.f - 1.f, Cv.y * 2.f - 1.f };
        #pragma unroll
        for (int x = 0; x < 2; ++x) {
            mid[x][0][0] = 0.5f * (llv[x] - a[x] - bq[x] + cq[x]);
            mid[x][0][1] = 0.5f * (llv[x] - a[x] + bq[x] - cq[x]);
            mid[x][1][0] = 0.5f * (llv[x] + a[x] - bq[x] - cq[x]);
            mid[x][1][1] = 0.5f * (llv[x] + a[x] + bq[x] + cq[x]);
        }
    }

    const float* h1b = hf1 + ((size_t)b * 9 + 3 * c) * (H2 * W2);
    float* ob = out + ((size_t)(b * 3 + c)) * (H3 * W3);

    #pragma unroll
    for (int p = 0; p < 2; ++p) {
        const int Hr = 2 * h + p;
        const float* rowp = h1b + (size_t)Hr * W2 + 2 * w0;
        // float4 covers (x=0,q=0),(x=0,q=1),(x=1,q=0),(x=1,q=1)
        float4 A = *(const float4*)(rowp);
        float4 Bv = *(const float4*)(rowp + H2 * W2);
        float4 Cv = *(const float4*)(rowp + 2 * H2 * W2);
        const float a[2][2]  = { {A.x * 2.f - 1.f,  A.y * 2.f - 1.f},  {A.z * 2.f - 1.f,  A.w * 2.f - 1.f} };
        const float bb[2][2] = { {Bv.x * 2.f - 1.f, Bv.y * 2.f - 1.f}, {Bv.z * 2.f - 1.f, Bv.w * 2.f - 1.f} };
        const float cc[2][2] = { {Cv.x * 2.f - 1.f, Cv.y * 2.f - 1.f}, {Cv.z * 2.f - 1.f, Cv.w * 2.f - 1.f} };
        #pragma unroll
        for (int r = 0; r < 2; ++r) {
            const float sr = r ? 1.f : -1.f;
            float* orow = ob + (size_t)(4 * h + 2 * p + r) * W3 + 4 * w0;
            #pragma unroll
            for (int x = 0; x < 2; ++x) {
                float4 o;
                o.x = 0.5f * (mid[x][p][0] + sr * a[x][0] - bb[x][0] - sr * cc[x][0]);
                o.y = 0.5f * (mid[x][p][0] + sr * a[x][0] + bb[x][0] + sr * cc[x][0]);
                o.z = 0.5f * (mid[x][p][1] + sr * a[x][1] - bb[x][1] - sr * cc[x][1]);
                o.w = 0.5f * (mid[x][p][1] + sr * a[x][1] + bb[x][1] + sr * cc[x][1]);
                *(float4*)(orow + 4 * x) = o;
            }
        }
    }
}

extern "C" void kernel_launch(void* const* d_in, const int* in_sizes, int n_in,
                              void* d_out, int out_size, void* d_ws, size_t ws_size,
                              hipStream_t stream) {
    (void)in_sizes; (void)n_in; (void)out_size;
    const float* fused = (const float*)d_in[0];
    const float* hf1   = (const float*)d_in[1];
    const float* hf2   = (const float*)d_in[2];
    const float* cw    = (const float*)d_in[3];
    const float* cb    = (const float*)d_in[4];
    float* out  = (float*)d_out;
    float* part = (float*)d_ws;

    const size_t need4 = (size_t)4 * LLSZ * sizeof(float);  // 12.6 MB
    dim3 cblk(64, 4, 1);
    const int iwtBlocks = (NB * 3 * H1 * (W1 / 2)) / 256;   // 1536

    if (ws_size >= need4) {
        dim3 cgrd(4, H1 / 4, NB);                           // 2048 blocks
        conv_part_kernel<16><<<cgrd, cblk, 0, stream>>>(fused, cw, part);
        iwt2_kernel<4><<<iwtBlocks, 256, 0, stream>>>(part, cb, hf2, hf1, out);
    } else {
        dim3 cgrd(1, H1 / 4, NB);
        conv_part_kernel<64><<<cgrd, cblk, 0, stream>>>(fused, cw, part);
        iwt2_kernel<1><<<iwtBlocks, 256, 0, stream>>>(part, cb, hf2, hf1, out);
    }
}

// Round 4
// 196.273 us; speedup vs baseline: 1.6811x; 1.6811x over previous
//
#include <hip/hip_runtime.h>
#include <cmath>

// Shapes:
//  fused  [16,64,128,128] f32
//  hf1    [16, 9,256,256] f32
//  hf2    [16, 9,128,128] f32
//  conv_w [3,64,3,3] f32, conv_b [3] f32
//  out    [16,3,512,512] f32
//
// Kernel A: conv partial sums over ic-chunks (NO tanh) -> d_ws [NCHUNK][16][3][128][128]
//   4-way ic split: 2048 blocks -> 32 waves/CU (round-2: 512 blocks was 21% occ, 68 us).
//   NO launch_bounds cap, NO manual pipeline: round-3's forced pipeline under a VGPR=32
//   cap spilled to scratch (WRITE_SIZE 295 MB) and ran 3x slower. TLP does the hiding.
// Kernel B: iwt2 sums partials + bias + tanh, then fused double inverse-Haar.

#define H1 128
#define W1 128
#define H2 256
#define W2 256
#define H3 512
#define W3 512
#define IN_CH 64
#define NB 16
#define PLANE (H1 * W1)            // 16384
#define LLSZ (NB * 3 * PLANE)      // 786432 floats per chunk

template <int ICP>
__global__ __launch_bounds__(256) void conv_part_kernel(
    const float* __restrict__ fused,
    const float* __restrict__ cw,
    float* __restrict__ part)
{
    // block (64,4); grid (64/ICP, 32, 16)
    const int tx    = threadIdx.x;
    const int ty    = threadIdx.y;
    const int chunk = blockIdx.x;
    const int h     = blockIdx.y * 4 + ty;
    const int b     = blockIdx.z;
    const int w0    = tx * 2;

    float acc[3][2];
    #pragma unroll
    for (int oc = 0; oc < 3; ++oc) { acc[oc][0] = 0.f; acc[oc][1] = 0.f; }

    const float* fc = fused + ((size_t)b * IN_CH + chunk * ICP) * PLANE;

    #pragma unroll 2
    for (int ic = 0; ic < ICP; ++ic) {
        const float* fp = fc + (size_t)ic * PLANE;
        float v[3][4];
        #pragma unroll
        for (int r = 0; r < 3; ++r) {
            const int hh = h + r - 1;
            const bool hv = ((unsigned)hh) < (unsigned)H1;
            const float* row = fp + hh * W1;
            v[r][0] = (hv && (w0 > 0)) ? row[w0 - 1] : 0.f;
            if (hv) {
                float2 m = *(const float2*)(row + w0);
                v[r][1] = m.x; v[r][2] = m.y;
            } else { v[r][1] = 0.f; v[r][2] = 0.f; }
            v[r][3] = (hv && ((w0 + 2) < W1)) ? row[w0 + 2] : 0.f;
        }
        #pragma unroll
        for (int oc = 0; oc < 3; ++oc) {
            const float* wp = cw + (oc * IN_CH + chunk * ICP + ic) * 9;  // uniform -> s_load
            #pragma unroll
            for (int kh = 0; kh < 3; ++kh) {
                #pragma unroll
                for (int kw = 0; kw < 3; ++kw) {
                    const float wv = wp[kh * 3 + kw];
                    acc[oc][0] = fmaf(v[kh][kw],     wv, acc[oc][0]);
                    acc[oc][1] = fmaf(v[kh][kw + 1], wv, acc[oc][1]);
                }
            }
        }
    }

    const size_t base = (size_t)chunk * LLSZ + (((size_t)b * 3) * H1 + h) * W1 + w0;
    #pragma unroll
    for (int oc = 0; oc < 3; ++oc) {
        float2 o; o.x = acc[oc][0]; o.y = acc[oc][1];
        *(float2*)(part + base + (size_t)oc * PLANE) = o;
    }
}

// Fused double inverse-Haar; 2 coarse px/thread; sums NCHUNK conv partials + bias + tanh.
template <int NCHUNK>
__global__ __launch_bounds__(256) void iwt2_kernel(
    const float* __restrict__ part,  // [NCHUNK][16][3][128][128]
    const float* __restrict__ cb,    // [3]
    const float* __restrict__ hf2,   // [16,9,128,128]
    const float* __restrict__ hf1,   // [16,9,256,256]
    float* __restrict__ out)         // [16,3,512,512]
{
    const int idx = blockIdx.x * 256 + threadIdx.x;   // 393216 total
    const int w0 = (idx & 63) * 2;                    // coarse w, even
    const int h  = (idx >> 6) & (H1 - 1);
    const int rest = idx >> 13;                       // 0..47
    const int c = rest % 3;
    const int b = rest / 3;

    // ll pair (pre-tanh partial sum)
    const size_t llbase = (((size_t)(b * 3 + c)) * H1 + h) * W1 + w0;
    float sx = 0.f, sy = 0.f;
    #pragma unroll
    for (int k = 0; k < NCHUNK; ++k) {
        float2 p = *(const float2*)(part + (size_t)k * LLSZ + llbase);
        sx += p.x; sy += p.y;
    }
    const float bias = cb[c];
    float llv[2];
    llv[0] = tanhf(sx + bias);
    llv[1] = tanhf(sy + bias);

    // hf2 -> mid[x][p][q] for the 2 coarse px
    const float* h2p = hf2 + (((size_t)b * 9 + 3 * c) * H1 + h) * W1 + w0;
    float mid[2][2][2];
    {
        const float2 A  = *(const float2*)(h2p);
        const float2 Bv = *(const float2*)(h2p + PLANE);
        const float2 Cv = *(const float2*)(h2p + 2 * PLANE);
        const float a[2]  = { A.x * 2.f - 1.f,  A.y * 2.f - 1.f };
        const float bq[2] = { Bv.x * 2.f - 1.f, Bv.y * 2.f - 1.f };
        const float cq[2] = { Cv.x * 2.f - 1.f, Cv.y * 2.f - 1.f };
        #pragma unroll
        for (int x = 0; x < 2; ++x) {
            mid[x][0][0] = 0.5f * (llv[x] - a[x] - bq[x] + cq[x]);
            mid[x][0][1] = 0.5f * (llv[x] - a[x] + bq[x] - cq[x]);
            mid[x][1][0] = 0.5f * (llv[x] + a[x] - bq[x] - cq[x]);
            mid[x][1][1] = 0.5f * (llv[x] + a[x] + bq[x] + cq[x]);
        }
    }

    const float* h1b = hf1 + ((size_t)b * 9 + 3 * c) * (H2 * W2);
    float* ob = out + ((size_t)(b * 3 + c)) * (H3 * W3);

    #pragma unroll
    for (int p = 0; p < 2; ++p) {
        const int Hr = 2 * h + p;
        const float* rowp = h1b + (size_t)Hr * W2 + 2 * w0;
        // float4 covers (x=0,q=0),(x=0,q=1),(x=1,q=0),(x=1,q=1)
        float4 A  = *(const float4*)(rowp);
        float4 Bv = *(const float4*)(rowp + H2 * W2);
        float4 Cv = *(const float4*)(rowp + 2 * H2 * W2);
        const float a[2][2]  = { {A.x * 2.f - 1.f,  A.y * 2.f - 1.f},  {A.z * 2.f - 1.f,  A.w * 2.f - 1.f} };
        const float bb[2][2] = { {Bv.x * 2.f - 1.f, Bv.y * 2.f - 1.f}, {Bv.z * 2.f - 1.f, Bv.w * 2.f - 1.f} };
        const float cc[2][2] = { {Cv.x * 2.f - 1.f, Cv.y * 2.f - 1.f}, {Cv.z * 2.f - 1.f, Cv.w * 2.f - 1.f} };
        #pragma unroll
        for (int r = 0; r < 2; ++r) {
            const float sr = r ? 1.f : -1.f;
            float* orow = ob + (size_t)(4 * h + 2 * p + r) * W3 + 4 * w0;
            #pragma unroll
            for (int x = 0; x < 2; ++x) {
                float4 o;
                o.x = 0.5f * (mid[x][p][0] + sr * a[x][0] - bb[x][0] - sr * cc[x][0]);
                o.y = 0.5f * (mid[x][p][0] + sr * a[x][0] + bb[x][0] + sr * cc[x][0]);
                o.z = 0.5f * (mid[x][p][1] + sr * a[x][1] - bb[x][1] - sr * cc[x][1]);
                o.w = 0.5f * (mid[x][p][1] + sr * a[x][1] + bb[x][1] + sr * cc[x][1]);
                *(float4*)(orow + 4 * x) = o;
            }
        }
    }
}

extern "C" void kernel_launch(void* const* d_in, const int* in_sizes, int n_in,
                              void* d_out, int out_size, void* d_ws, size_t ws_size,
                              hipStream_t stream) {
    (void)in_sizes; (void)n_in; (void)out_size;
    const float* fused = (const float*)d_in[0];
    const float* hf1   = (const float*)d_in[1];
    const float* hf2   = (const float*)d_in[2];
    const float* cw    = (const float*)d_in[3];
    const float* cb    = (const float*)d_in[4];
    float* out  = (float*)d_out;
    float* part = (float*)d_ws;

    const size_t need4 = (size_t)4 * LLSZ * sizeof(float);  // 12.6 MB
    dim3 cblk(64, 4, 1);
    const int iwtBlocks = (NB * 3 * H1 * (W1 / 2)) / 256;   // 1536

    if (ws_size >= need4) {
        dim3 cgrd(4, H1 / 4, NB);                           // 2048 blocks
        conv_part_kernel<16><<<cgrd, cblk, 0, stream>>>(fused, cw, part);
        iwt2_kernel<4><<<iwtBlocks, 256, 0, stream>>>(part, cb, hf2, hf1, out);
    } else {
        dim3 cgrd(1, H1 / 4, NB);
        conv_part_kernel<64><<<cgrd, cblk, 0, stream>>>(fused, cw, part);
        iwt2_kernel<1><<<iwtBlocks, 256, 0, stream>>>(part, cb, hf2, hf1, out);
    }
}

// Round 5
// 169.050 us; speedup vs baseline: 1.9518x; 1.1610x over previous
//
#include <hip/hip_runtime.h>
#include <cmath>

// Shapes:
//  fused  [16,64,128,128] f32
//  hf1    [16, 9,256,256] f32
//  hf2    [16, 9,128,128] f32
//  conv_w [3,64,3,3] f32, conv_b [3] f32
//  out    [16,3,512,512] f32
//
// Pipeline (ws >= 15.7 MB path):
//  K1 conv_part<16>: 4-way ic-split partial conv -> part [4][16][3][128][128] (12.6 MB)
//  K2 reduce_tanh:   ll = tanh(sum part + bias)  -> ll at part+4*LLSZ (3.1 MB)
//  K3 iwt_fine<0>:   one thread per out float4, double inverse-Haar from ll/hf2/hf1.
// R4 post-mortem: iwt2 (coarse, 1 thr = 32 out px) was ~133 us across all rounds
// (serial chain, 6 blocks/CU); conv latency-bound at VALUBusy 20%.

#define H1 128
#define W1 128
#define H2 256
#define W2 256
#define H3 512
#define W3 512
#define IN_CH 64
#define NB 16
#define PLANE (H1 * W1)            // 16384
#define LLSZ (NB * 3 * PLANE)      // 786432 floats per chunk

template <int ICP>
__global__ __launch_bounds__(256) void conv_part_kernel(
    const float* __restrict__ fused,
    const float* __restrict__ cw,
    float* __restrict__ part)
{
    // block (64,4): one wave per image row (tx=lane=w-pair), ty = row within tile.
    // grid (IN_CH/ICP, 32, 16)
    const int tx    = threadIdx.x;
    const int ty    = threadIdx.y;
    const int chunk = blockIdx.x;
    const int h     = blockIdx.y * 4 + ty;
    const int b     = blockIdx.z;
    const int w0    = tx * 2;

    float acc[3][2];
    #pragma unroll
    for (int oc = 0; oc < 3; ++oc) { acc[oc][0] = 0.f; acc[oc][1] = 0.f; }

    const float* fc = fused + ((size_t)b * IN_CH + chunk * ICP) * PLANE;

    // Only 3 float2 loads per ic; halo comes from neighbor lanes via shuffle.
    auto ld = [&](float2 m[3], int ic) {
        const float* fp = fc + (size_t)ic * PLANE;
        #pragma unroll
        for (int r = 0; r < 3; ++r) {
            const int hh = h + r - 1;
            if (((unsigned)hh) < (unsigned)H1) {
                m[r] = *(const float2*)(fp + hh * W1 + w0);
            } else {
                m[r].x = 0.f; m[r].y = 0.f;
            }
        }
    };

    auto comp = [&](const float2 m[3], int ic) {
        float v[3][4];
        #pragma unroll
        for (int r = 0; r < 3; ++r) {
            float left  = __shfl_up(m[r].y, 1, 64);
            float right = __shfl_down(m[r].x, 1, 64);
            if (tx == 0)  left = 0.f;    // w = -1
            if (tx == 63) right = 0.f;   // w = 128
            v[r][0] = left; v[r][1] = m[r].x; v[r][2] = m[r].y; v[r][3] = right;
        }
        #pragma unroll
        for (int oc = 0; oc < 3; ++oc) {
            const float* wp = cw + (oc * IN_CH + chunk * ICP + ic) * 9;  // uniform -> s_load
            #pragma unroll
            for (int kh = 0; kh < 3; ++kh) {
                #pragma unroll
                for (int kw = 0; kw < 3; ++kw) {
                    const float wv = wp[kh * 3 + kw];
                    acc[oc][0] = fmaf(v[kh][kw],     wv, acc[oc][0]);
                    acc[oc][1] = fmaf(v[kh][kw + 1], wv, acc[oc][1]);
                }
            }
        }
    };

    // 2-deep software pipeline (NO launch_bounds cap -> no spill; R3's spill came
    // from the min-waves cap).
    float2 A[3], B[3];
    ld(A, 0);
    for (int ic = 0; ic < ICP; ic += 2) {
        ld(B, ic + 1);
        comp(A, ic);
        if (ic + 2 < ICP) ld(A, ic + 2);
        comp(B, ic + 1);
    }

    const size_t base = (size_t)chunk * LLSZ + (((size_t)b * 3) * H1 + h) * W1 + w0;
    #pragma unroll
    for (int oc = 0; oc < 3; ++oc) {
        float2 o; o.x = acc[oc][0]; o.y = acc[oc][1];
        *(float2*)(part + base + (size_t)oc * PLANE) = o;
    }
}

// part[4] -> ll = tanh(sum + bias). 1 thread = 4 px.
__global__ __launch_bounds__(256) void reduce_tanh_kernel(
    const float* __restrict__ part,
    const float* __restrict__ cb,
    float* __restrict__ ll)
{
    const int j = blockIdx.x * 256 + threadIdx.x;        // 196608
    const int c = (j >> 12) % 3;                         // plane = j/4096, c = plane%3
    float4 s = *(const float4*)(part + 4 * (size_t)j);
    #pragma unroll
    for (int k = 1; k < 4; ++k) {
        float4 p = *(const float4*)(part + (size_t)k * LLSZ + 4 * (size_t)j);
        s.x += p.x; s.y += p.y; s.z += p.z; s.w += p.w;
    }
    const float bias = cb[c];
    float4 o;
    o.x = tanhf(s.x + bias); o.y = tanhf(s.y + bias);
    o.z = tanhf(s.z + bias); o.w = tanhf(s.w + bias);
    *(float4*)(ll + 4 * (size_t)j) = o;
}

// One thread per output float4 (out col group = coarse col k). 3.15M threads.
// NCHUNK==0: llp is pre-tanh'd ll. NCHUNK>=1: llp is part; sum+bias+tanh inline.
template <int NCHUNK>
__global__ __launch_bounds__(256) void iwt_fine_kernel(
    const float* __restrict__ llp,
    const float* __restrict__ cb,
    const float* __restrict__ hf2,   // [16,9,128,128]
    const float* __restrict__ hf1,   // [16,9,256,256]
    float* __restrict__ out)         // [16,3,512,512]
{
    const int idx = blockIdx.x * 256 + threadIdx.x;   // 3145728
    const int k    = idx & 127;          // coarse col
    const int H    = (idx >> 7) & 511;   // out row
    const int rest = idx >> 16;          // 0..47
    const int c = rest % 3;
    const int b = rest / 3;
    const int h  = H >> 2;               // coarse row
    const int p  = (H >> 1) & 1;         // level-1 sub-row
    const int r  = H & 1;                // level-0 sub-row
    const int Hr = H >> 1;               // level-1 row

    const size_t llidx = (((size_t)(b * 3 + c)) * H1 + h) * W1 + k;
    float llv;
    if constexpr (NCHUNK == 0) {
        llv = llp[llidx];
    } else {
        float s = 0.f;
        #pragma unroll
        for (int kk = 0; kk < NCHUNK; ++kk) s += llp[(size_t)kk * LLSZ + llidx];
        llv = tanhf(s + cb[c]);
    }

    const float* h2p = hf2 + (((size_t)(b * 9 + 3 * c)) * H1 + h) * W1 + k;
    const float a2 = h2p[0]         * 2.f - 1.f;   // LH
    const float b2 = h2p[PLANE]     * 2.f - 1.f;   // HL
    const float c2 = h2p[2 * PLANE] * 2.f - 1.f;   // HH
    const float sp = p ? 1.f : -1.f;
    const float m0 = 0.5f * (llv + sp * a2 - b2 - sp * c2);   // level-1 col 2k
    const float m1 = 0.5f * (llv + sp * a2 + b2 + sp * c2);   // level-1 col 2k+1

    const float* h1p = hf1 + ((size_t)(b * 9 + 3 * c)) * (H2 * W2) + (size_t)Hr * W2 + 2 * k;
    const float2 A  = *(const float2*)(h1p);
    const float2 Bv = *(const float2*)(h1p + H2 * W2);
    const float2 Cv = *(const float2*)(h1p + 2 * H2 * W2);
    const float a0 = A.x  * 2.f - 1.f, a1 = A.y  * 2.f - 1.f;
    const float b0 = Bv.x * 2.f - 1.f, b1 = Bv.y * 2.f - 1.f;
    const float c0 = Cv.x * 2.f - 1.f, c1 = Cv.y * 2.f - 1.f;
    const float sr = r ? 1.f : -1.f;

    float4 o;
    o.x = 0.5f * (m0 + sr * a0 - b0 - sr * c0);
    o.y = 0.5f * (m0 + sr * a0 + b0 + sr * c0);
    o.z = 0.5f * (m1 + sr * a1 - b1 - sr * c1);
    o.w = 0.5f * (m1 + sr * a1 + b1 + sr * c1);
    *(float4*)(out + (((size_t)(b * 3 + c)) * H3 + H) * W3 + 4 * k) = o;
}

extern "C" void kernel_launch(void* const* d_in, const int* in_sizes, int n_in,
                              void* d_out, int out_size, void* d_ws, size_t ws_size,
                              hipStream_t stream) {
    (void)in_sizes; (void)n_in; (void)out_size;
    const float* fused = (const float*)d_in[0];
    const float* hf1   = (const float*)d_in[1];
    const float* hf2   = (const float*)d_in[2];
    const float* cw    = (const float*)d_in[3];
    const float* cb    = (const float*)d_in[4];
    float* out  = (float*)d_out;
    float* part = (float*)d_ws;

    const size_t need_part4 = (size_t)4 * LLSZ * sizeof(float);  // 12.6 MB
    const size_t need_full  = (size_t)5 * LLSZ * sizeof(float);  // 15.7 MB
    dim3 cblk(64, 4, 1);
    const int iwtBlocks = (NB * 3 * H3 * W3 / 4) / 256;          // 12288

    if (ws_size >= need_full) {
        float* ll = part + (size_t)4 * LLSZ;
        dim3 cgrd(4, H1 / 4, NB);                                // 2048 blocks
        conv_part_kernel<16><<<cgrd, cblk, 0, stream>>>(fused, cw, part);
        reduce_tanh_kernel<<<LLSZ / 4 / 256, 256, 0, stream>>>(part, cb, ll);
        iwt_fine_kernel<0><<<iwtBlocks, 256, 0, stream>>>(ll, cb, hf2, hf1, out);
    } else if (ws_size >= need_part4) {
        dim3 cgrd(4, H1 / 4, NB);
        conv_part_kernel<16><<<cgrd, cblk, 0, stream>>>(fused, cw, part);
        iwt_fine_kernel<4><<<iwtBlocks, 256, 0, stream>>>(part, cb, hf2, hf1, out);
    } else {
        dim3 cgrd(1, H1 / 4, NB);                                // 512 blocks
        conv_part_kernel<64><<<cgrd, cblk, 0, stream>>>(fused, cw, part);
        iwt_fine_kernel<1><<<iwtBlocks, 256, 0, stream>>>(part, cb, hf2, hf1, out);
    }
}